// Round 8
// baseline (331.126 us; speedup 1.0000x reference)
//
#include <hip/hip_runtime.h>
#include <hip/hip_cooperative_groups.h>
#include <cfloat>
#include <cstdint>

namespace cg = cooperative_groups;

#define NSEG 512
#define C 21
#define PPB 512                   // points per chunk
#define NCHK 64                   // n/PPB point chunks == m/256 sptid chunks
#define EPS_PICK 1e-3f            // >= 2*deltaM (MFMA emu) and >= deltaM+delta32 (filter)

typedef short short8 __attribute__((ext_vector_type(8)));     // 8 bf16 (MFMA A/B frag)
typedef float f32x4 __attribute__((ext_vector_type(4)));      // MFMA acc

// truncate r to bf16 (exact split: hi takes the top bits, r -= hi exact in f32)
__device__ inline unsigned short bsplit(float& r) {
    unsigned int u = __float_as_uint(r) & 0xFFFF0000u;
    r -= __uint_as_float(u);
    return (unsigned short)(u >> 16);
}

// ONE cooperative kernel, 256 blocks x 512 threads (1 block/CU), 4 phases:
//  A: prep  (pts4 + A-side split | B-side split | sptid histogram)
//  B: block0 segment-offset scan, then emulated-f32 MFMA distance + per-chunk min
//  C: wave-per-query exact pick (gmin/ballot-mask/f64 resolve)  ||  counting-sort scatter
//  D: wave-per-segment score-sum argmax + label writeback
// K-slot layout (K=32, 21 used), per coord c (a=-2*p_c, b=q_c):
//   slots 6c..6c+5: A=[ah,ah,al,al,ah,a2]  B=[bh,bl,bh,bl,b2,bh]
//   slots 18..20:   A=|p|^2 hi/lo/lo2  B=[1,1,1];  slots 21..31: 0
__global__ __launch_bounds__(512)
void mega(const float* __restrict__ pts, const float* __restrict__ dpts,
          const int* __restrict__ sptids, const float* __restrict__ scores,
          int n, int m,
          float4* __restrict__ pts4, short8* __restrict__ ptsplit,
          short8* __restrict__ qsplit, float* __restrict__ pbvT,
          int* __restrict__ nn_idx, int* __restrict__ chunkhistT,
          int* __restrict__ chunkoffT, int* __restrict__ sorted_orig,
          float* __restrict__ out)
{
    cg::grid_group grid = cg::this_grid();
    __shared__ short8 abuf[2048];                 // 32 KB, reused per phase
    __shared__ int tot[NSEG];                     // scan scratch (block 0)
    const int bid = blockIdx.x, t = threadIdx.x;
    const int wave = t >> 6, lane = t & 63;

    // ================= Phase A: prep =================
    {
        int g = bid * 512 + t;
        if (g < n) {                              // point split (blocks 0..63)
            int i = g;
            float x = pts[i * 3 + 0], y = pts[i * 3 + 1], z = pts[i * 3 + 2];
            pts4[i] = make_float4(x, y, z, fmaf(x, x, fmaf(y, y, z * z)));
            unsigned short sl[24];
#pragma unroll
            for (int c = 0; c < 3; c++) {
                float a = -2.f * ((c == 0) ? x : (c == 1) ? y : z);   // exact in f32
                float r = a;
                unsigned short ah = bsplit(r), al = bsplit(r), a2 = bsplit(r);
                sl[c * 6 + 0] = ah; sl[c * 6 + 1] = ah; sl[c * 6 + 2] = al;
                sl[c * 6 + 3] = al; sl[c * 6 + 4] = ah; sl[c * 6 + 5] = a2;
            }
            double pr = (double)x * x + (double)y * y + (double)z * z;
#pragma unroll
            for (int l = 0; l < 3; l++) {                             // |p|^2 hi/lo/lo2
                float f = (float)pr;
                unsigned int u = __float_as_uint(f) & 0xFFFF0000u;
                pr -= (double)__uint_as_float(u);
                sl[18 + l] = (unsigned short)(u >> 16);
            }
            sl[21] = 0; sl[22] = 0; sl[23] = 0;
            size_t base = (size_t)(i >> 4) * 64 + (i & 15);           // frag-major
            short8 g0, g1, g2, gz;
#pragma unroll
            for (int j = 0; j < 8; j++) { g0[j] = (short)sl[j]; g1[j] = (short)sl[8 + j]; g2[j] = (short)sl[16 + j]; gz[j] = 0; }
            ptsplit[base + 0] = g0; ptsplit[base + 16] = g1;
            ptsplit[base + 32] = g2; ptsplit[base + 48] = gz;
        } else if (g - n < m) {                   // query split (blocks 64..95)
            int q = g - n;
            unsigned short sl[24];
#pragma unroll
            for (int c = 0; c < 3; c++) {
                float b = dpts[q * 3 + c];
                float r = b;
                unsigned short bh = bsplit(r), bl = bsplit(r), b2 = bsplit(r);
                sl[c * 6 + 0] = bh; sl[c * 6 + 1] = bl; sl[c * 6 + 2] = bh;
                sl[c * 6 + 3] = bl; sl[c * 6 + 4] = b2; sl[c * 6 + 5] = bh;
            }
            sl[18] = 0x3F80; sl[19] = 0x3F80; sl[20] = 0x3F80;        // bf16 1.0
            sl[21] = 0; sl[22] = 0; sl[23] = 0;
            size_t base = (size_t)(q >> 4) * 64 + (q & 15);
            short8 g0, g1, g2, gz;
#pragma unroll
            for (int j = 0; j < 8; j++) { g0[j] = (short)sl[j]; g1[j] = (short)sl[8 + j]; g2[j] = (short)sl[16 + j]; gz[j] = 0; }
            qsplit[base + 0] = g0; qsplit[base + 16] = g1;
            qsplit[base + 32] = g2; qsplit[base + 48] = gz;
        }
        int hb0 = (n + m) >> 9;                   // first histogram block (96)
        if (bid >= hb0 && bid < hb0 + (NCHK >> 1)) {   // 32 blocks x 2 chunks
            int* h = (int*)abuf;                  // 2 x NSEG ints
            for (int j = t; j < 2 * NSEG; j += 512) h[j] = 0;
            __syncthreads();
            int chpair = (bid - hb0) * 2;
            int idx = (chpair + (t >> 8)) * 256 + (t & 255);
            if (idx < m) atomicAdd(&h[(t >> 8) * NSEG + sptids[idx]], 1);
            __syncthreads();
            chunkhistT[t * NCHK + chpair]     = h[t];          // transposed [seg][ch]
            chunkhistT[t * NCHK + chpair + 1] = h[NSEG + t];
        }
    }
    __threadfence();
    grid.sync();

    // ================= Phase B: scan (block 0) + MFMA =================
    if (bid == 0) {                               // segment-offset scan, 512 thr == NSEG
        int s = t;
        const int4* row = (const int4*)(chunkhistT + s * NCHK);
        int sum = 0;
#pragma unroll
        for (int c4 = 0; c4 < 16; c4++) { int4 v = row[c4]; sum += v.x + v.y + v.z + v.w; }
        tot[s] = sum;
        __syncthreads();
        int incl = sum;
        for (int off = 1; off < NSEG; off <<= 1) {
            int add = (s >= off) ? tot[s - off] : 0;
            __syncthreads();
            incl += add; tot[s] = incl;
            __syncthreads();
        }
        int running = incl - sum;                 // exclusive segment base
        int4* orow = (int4*)(chunkoffT + s * NCHK);
#pragma unroll
        for (int c4 = 0; c4 < 16; c4++) {
            int4 v = row[c4]; int4 o;
            o.x = running; running += v.x;
            o.y = running; running += v.y;
            o.z = running; running += v.z;
            o.w = running; running += v.w;
            orow[c4] = o;
        }
        __syncthreads();
    }
    {   // MFMA distance + per-chunk min (unchanged, validated R6/R7)
        int qb = bid & 15, cgr = bid >> 4;
        short8 bq[8];
        int qtbase = qb * 64 + wave * 8;
#pragma unroll
        for (int f = 0; f < 8; f++) bq[f] = qsplit[(size_t)(qtbase + f) * 64 + lane];

        const float4* psrc = (const float4*)ptsplit;
        float4* lbuf = (float4*)abuf;
        int c0 = cgr * 4;
        float4 st0, st1, st2, st3;
        st0 = psrc[(size_t)c0 * 2048 + 0 * 512 + t];
        st1 = psrc[(size_t)c0 * 2048 + 1 * 512 + t];
        st2 = psrc[(size_t)c0 * 2048 + 2 * 512 + t];
        st3 = psrc[(size_t)c0 * 2048 + 3 * 512 + t];
        lbuf[0 * 512 + t] = st0; lbuf[1 * 512 + t] = st1;
        lbuf[2 * 512 + t] = st2; lbuf[3 * 512 + t] = st3;
        __syncthreads();

        for (int cl = 0; cl < 4; cl++) {
            int pc = c0 + cl;
            if (cl < 3) {                         // issue next-chunk loads early
                st0 = psrc[(size_t)(pc + 1) * 2048 + 0 * 512 + t];
                st1 = psrc[(size_t)(pc + 1) * 2048 + 1 * 512 + t];
                st2 = psrc[(size_t)(pc + 1) * 2048 + 2 * 512 + t];
                st3 = psrc[(size_t)(pc + 1) * 2048 + 3 * 512 + t];
            }
            float run[8];
#pragma unroll
            for (int f = 0; f < 8; f++) run[f] = FLT_MAX;
            f32x4 zero = {0.f, 0.f, 0.f, 0.f};
#pragma unroll 4
            for (int tt = 0; tt < 32; tt++) {
                short8 a = abuf[tt * 64 + lane];  // lane-contiguous b128: conflict-free
#pragma unroll
                for (int f = 0; f < 8; f++) {
                    f32x4 acc = __builtin_amdgcn_mfma_f32_16x16x32_bf16(a, bq[f], zero, 0, 0, 0);
                    float t1 = fminf(fminf(acc[0], acc[1]), acc[2]);          // v_min3
                    run[f] = fminf(fminf(t1, acc[3]), run[f]);                // v_min3
                }
            }
#pragma unroll
            for (int f = 0; f < 8; f++) {         // merge 4 row-groups, write chunk min
                float v = run[f];
                v = fminf(v, __shfl_xor(v, 16, 64));
                v = fminf(v, __shfl_xor(v, 32, 64));
                if (lane < 16)
                    pbvT[(size_t)(qb * 1024 + wave * 128 + f * 16 + lane) * 64 + pc] = v;
            }
            __syncthreads();
            if (cl < 3) {
                lbuf[0 * 512 + t] = st0; lbuf[1 * 512 + t] = st1;
                lbuf[2 * 512 + t] = st2; lbuf[3 * 512 + t] = st3;
                __syncthreads();
            }
        }
    }
    __threadfence();
    grid.sync();

    // ================= Phase C: pick (all waves) || scatter (blocks 0..63) =================
    {
        int W = bid * 8 + wave;                   // 0..2047, 8 queries each
#pragma unroll 1
        for (int k = 0; k < 8; k++) {
            int q = W * 8 + k;
            if (q >= m) continue;
            float myv = pbvT[(size_t)q * 64 + lane];      // chunk `lane` min (coalesced)
            float g1 = myv;
#pragma unroll
            for (int off = 1; off < 64; off <<= 1) g1 = fminf(g1, __shfl_xor(g1, off, 64));
            float thr = g1 + EPS_PICK;
            unsigned long long msk = __ballot(myv <= thr);    // bit pc == chunk qualifies

            float fx = dpts[q * 3 + 0], fy = dpts[q * 3 + 1], fz = dpts[q * 3 + 2];
            float fm2x = -2.f * fx, fm2y = -2.f * fy, fm2z = -2.f * fz;
            double m2x = -2.0 * (double)fx, m2y = -2.0 * (double)fy, m2z = -2.0 * (double)fz;
            double best = 1e308; int bi = 0x7fffffff;
            while (msk) {
                int pc = __builtin_ctzll(msk); msk &= msk - 1;
                int base = pc * PPB + lane;
#pragma unroll
                for (int r2 = 0; r2 < PPB / 64; r2++) {
                    int i = base + r2 * 64;
                    if (i < n) {
                        float4 p = pts4[i];
                        float v = fmaf(p.x, fm2x, fmaf(p.y, fm2y, fmaf(p.z, fm2z, p.w)));
                        if (v <= thr) {
                            double ps = (double)p.x * p.x + (double)p.y * p.y + (double)p.z * p.z;
                            double dv = fma((double)p.x, m2x, fma((double)p.y, m2y,
                                        fma((double)p.z, m2z, ps)));
                            if (dv < best || (dv == best && i < bi)) { best = dv; bi = i; }
                        }
                    }
                }
            }
#pragma unroll
            for (int off = 32; off; off >>= 1) {
                double ov = __shfl_down(best, off, 64);
                int oi = __shfl_down(bi, off, 64);
                if (ov < best || (ov == best && oi < bi)) { best = ov; bi = oi; }
            }
            if (lane == 0) nn_idx[q] = bi;
        }
    }
    if (bid < NCHK) {                             // stable counting-sort scatter
        int* segs = (int*)abuf;                   // abuf free (pick uses no LDS)
        int i = bid * 256 + (t & 255);
        int seg = -1;
        if (t < 256) { seg = (i < m) ? sptids[i] : -1; segs[t] = seg; }
        __syncthreads();
        if (t < 256 && i < m) {
            int rank = 0;
            for (int j = 0; j < t; j++) rank += (segs[j] == seg) ? 1 : 0;  // stable
            int pos = chunkoffT[seg * NCHK + bid] + rank;
            out[pos * 3 + 0] = dpts[i * 3 + 0];
            out[pos * 3 + 1] = dpts[i * 3 + 1];
            out[pos * 3 + 2] = dpts[i * 3 + 2];
            sorted_orig[pos] = i;                 // nn_idx NOT read here (still in flight)
        }
    }
    __threadfence();
    grid.sync();

    // ================= Phase D: seg argmax + label writeback =================
    {
        int W = bid * 8 + wave;
        if (W < NSEG) {
            int s = W;
            int base = chunkoffT[s * NCHK];       // chunk-0 offset == segment base
            int end  = (s == NSEG - 1) ? m : chunkoffT[(s + 1) * NCHK];
            double acc[C];
#pragma unroll
            for (int c = 0; c < C; c++) acc[c] = 0.0;
            for (int j = base + lane; j < end; j += 64) {
                const float* sp = scores + (size_t)nn_idx[sorted_orig[j]] * C;
#pragma unroll
                for (int c = 0; c < C; c++) acc[c] += (double)sp[c];
            }
#pragma unroll
            for (int c = 0; c < C; c++) {
                for (int off = 32; off; off >>= 1) acc[c] += __shfl_down(acc[c], off, 64);
            }
            int best = 0;
            if (lane == 0) {
                double bv = acc[0];
                for (int c = 1; c < C; c++)
                    if (acc[c] > bv) { bv = acc[c]; best = c; }   // strict >: first max wins
            }
            best = __shfl(best, 0, 64);
            float fb = (float)best;
            for (int j = base + lane; j < end; j += 64)
                out[(size_t)m * 3 + sorted_orig[j]] = fb;
        }
    }
}

extern "C" void kernel_launch(void* const* d_in, const int* in_sizes, int n_in,
                              void* d_out, int out_size, void* d_ws, size_t ws_size,
                              hipStream_t stream) {
    const float* points = (const float*)d_in[0];
    const float* scores = (const float*)d_in[1];
    const float* dpts   = (const float*)d_in[2];
    const int*   sptids = (const int*)d_in[3];

    int n = in_sizes[0] / 3;          // 32768
    int m = in_sizes[2] / 3;          // 16384

    char* ws = (char*)d_ws;
    short8* ptsplit    = (short8*)ws;  ws += (size_t)n * 64;
    short8* qsplit     = (short8*)ws;  ws += (size_t)m * 64;
    float4* pts4       = (float4*)ws;  ws += (size_t)n * sizeof(float4);
    float*  pbvT       = (float*)ws;   ws += (size_t)m * NCHK * sizeof(float);
    int*    nn_idx     = (int*)ws;     ws += (size_t)m * sizeof(int);
    int*    chunkhistT = (int*)ws;     ws += (size_t)NSEG * NCHK * sizeof(int);
    int*    chunkoffT  = (int*)ws;     ws += (size_t)NSEG * NCHK * sizeof(int);
    int*    sorted_orig= (int*)ws;     ws += (size_t)m * sizeof(int);
    float*  outp       = (float*)d_out;

    void* args[] = { (void*)&points, (void*)&dpts, (void*)&sptids, (void*)&scores,
                     (void*)&n, (void*)&m,
                     (void*)&pts4, (void*)&ptsplit, (void*)&qsplit, (void*)&pbvT,
                     (void*)&nn_idx, (void*)&chunkhistT, (void*)&chunkoffT,
                     (void*)&sorted_orig, (void*)&outp };
    hipLaunchCooperativeKernel((const void*)mega, dim3(256), dim3(512), args, 0, stream);
}

// Round 9
// 297.090 us; speedup vs baseline: 1.1146x; 1.1146x over previous
//
#include <hip/hip_runtime.h>
#include <cfloat>
#include <cstdint>

#define NSEG 512
#define C 21
#define PPB 512                   // points per chunk
#define NCHK 64                   // n/PPB point chunks == m/256 sptid chunks
#define EPS_PICK 1e-3f            // >= 2*deltaM (MFMA emu) and >= deltaM+delta32 (filter)
#define FPSCALE 1099511627776.0   // 2^40 fixed-point scale for deterministic int64 sums

typedef short short8 __attribute__((ext_vector_type(8)));     // 8 bf16 (MFMA A/B frag)
typedef float f32x4 __attribute__((ext_vector_type(4)));      // MFMA acc

// truncate r to bf16 (exact split: hi takes the top bits, r -= hi exact in f32)
__device__ inline unsigned short bsplit(float& r) {
    unsigned int u = __float_as_uint(r) & 0xFFFF0000u;
    r -= __uint_as_float(u);
    return (unsigned short)(u >> 16);
}

// ===================== K1: compute =====================
// bid 0..255   : MFMA blocks (self-staging bf16 splits from raw pts/dpts)
// bid 256..319 : scatter blocks (self-contained counting sort of d_points)
// bid 320      : zero segsum + done counter
// K-slot layout (K=32, 21 used), per coord c (a=-2*p_c, b=q_c):
//   slots 6c..6c+5: A=[ah,ah,al,al,ah,a2]  B=[bh,bl,bh,bl,b2,bh]
//   slots 18..20:   A=|p|^2 hi/lo/lo2  B=[1,1,1];  slots 21..31: 0
__global__ __launch_bounds__(512)
void compute(const float* __restrict__ pts, const float* __restrict__ dpts,
             const int* __restrict__ sptids,
             float4* __restrict__ pts4, float* __restrict__ pbvT,
             long long* __restrict__ segsum, int* __restrict__ done,
             float* __restrict__ out, int n, int m)
{
    __shared__ short8 abuf[2048];                 // 32 KB (mfma A-tile / scatter scratch)
    const int bid = blockIdx.x, t = threadIdx.x;
    const int wave = t >> 6, lane = t & 63;

    if (bid >= 256) {
        if (bid == 256 + NCHK) {                  // ---- zero block ----
            for (int j = t; j < NSEG * C; j += 512) segsum[j] = 0;
            if (t == 0) *done = 0;
            return;
        }
        // ---- scatter block sb: self-contained stable counting sort ----
        int sb = bid - 256;
        int* Hb = (int*)abuf;                     // [512] counts with idx < sb*256
        int* Ht = Hb + NSEG;                      // [512] total counts
        int* segs = Ht + NSEG;                    // [256] this chunk's sptids
        Hb[t] = 0; Ht[t] = 0;
        __syncthreads();
        int before = sb * 256;
        for (int idx = t; idx < m; idx += 512) {  // 32 iters; integer LDS atomics
            int s = sptids[idx];
            atomicAdd(&Ht[s], 1);
            if (idx < before) atomicAdd(&Hb[s], 1);
        }
        __syncthreads();
        int s = t;
        int mycnt = Ht[s], myHb = Hb[s];
        int incl = mycnt;                         // inclusive scan of totals (in place)
        for (int off = 1; off < NSEG; off <<= 1) {
            int add = (s >= off) ? Ht[s - off] : 0;
            __syncthreads();
            incl += add; Ht[s] = incl;
            __syncthreads();
        }
        Hb[s] = (incl - mycnt) + myHb;            // seg write base for THIS chunk
        __syncthreads();
        if (t < 256) {
            int i = sb * 256 + t;
            segs[t] = (i < m) ? sptids[i] : -1;
        }
        __syncthreads();
        if (t < 256) {
            int i = sb * 256 + t;
            if (i < m) {
                int seg = segs[t];
                int rank = 0;
                for (int j = 0; j < t; j++) rank += (segs[j] == seg) ? 1 : 0;  // stable
                int pos = Hb[seg] + rank;
                out[pos * 3 + 0] = dpts[i * 3 + 0];
                out[pos * 3 + 1] = dpts[i * 3 + 1];
                out[pos * 3 + 2] = dpts[i * 3 + 2];
            }
        }
        return;
    }

    // ---- MFMA block: emulated-f32 distance matmul + per-chunk min ----
    int qb = bid & 15, cgr = bid >> 4;

    short8 bq[8];                                 // B-frags computed from raw dpts
    {
        const short ONE = (short)0x3F80;          // bf16 1.0
#pragma unroll
        for (int f = 0; f < 8; f++) {
            int qf = qb * 1024 + wave * 128 + f * 16 + (lane & 15);
            float b0 = dpts[qf * 3 + 0], b1 = dpts[qf * 3 + 1], b2c = dpts[qf * 3 + 2];
            float r;
            r = b0;  unsigned short bh0 = bsplit(r), bl0 = bsplit(r), b20 = bsplit(r);
            r = b1;  unsigned short bh1 = bsplit(r), bl1 = bsplit(r), b21 = bsplit(r);
            r = b2c; unsigned short bh2 = bsplit(r), bl2 = bsplit(r), b22 = bsplit(r);
            short8 g0 = {(short)bh0,(short)bl0,(short)bh0,(short)bl0,(short)b20,(short)bh0,(short)bh1,(short)bl1};
            short8 g1 = {(short)bh1,(short)bl1,(short)b21,(short)bh1,(short)bh2,(short)bl2,(short)bh2,(short)bl2};
            short8 g2 = {(short)b22,(short)bh2,ONE,ONE,ONE,0,0,0};
            short8 gz = {0,0,0,0,0,0,0,0};
            int g = lane >> 4;
            bq[f] = (g == 0) ? g0 : (g == 1) ? g1 : (g == 2) ? g2 : gz;
        }
    }

    int c0 = cgr * 4;
    int i0 = c0 * PPB + t;
    float px = pts[i0 * 3 + 0], py = pts[i0 * 3 + 1], pz = pts[i0 * 3 + 2];

    for (int cl = 0; cl < 4; cl++) {
        int pc = c0 + cl;
        if (cl) __syncthreads();                  // prior MFMA readers done with abuf
        {   // stage point t of this chunk: compute A-slots, write frag-major LDS
            float x = px, y = py, z = pz;
            float r;
            float a0 = -2.f * x, a1 = -2.f * y, a2f = -2.f * z;   // exact in f32
            r = a0;  unsigned short ah0 = bsplit(r), al0 = bsplit(r), a20 = bsplit(r);
            r = a1;  unsigned short ah1 = bsplit(r), al1 = bsplit(r), a21 = bsplit(r);
            r = a2f; unsigned short ah2 = bsplit(r), al2 = bsplit(r), a22 = bsplit(r);
            double pr = (double)x * x + (double)y * y + (double)z * z;
            float f0 = (float)pr;
            unsigned int u0 = __float_as_uint(f0) & 0xFFFF0000u;
            pr -= (double)__uint_as_float(u0);
            float f1 = (float)pr;
            unsigned int u1 = __float_as_uint(f1) & 0xFFFF0000u;
            pr -= (double)__uint_as_float(u1);
            float f2 = (float)pr;
            unsigned int u2 = __float_as_uint(f2) & 0xFFFF0000u;
            unsigned short s0 = (unsigned short)(u0 >> 16);
            unsigned short s1 = (unsigned short)(u1 >> 16);
            unsigned short s2 = (unsigned short)(u2 >> 16);
            short8 g0 = {(short)ah0,(short)ah0,(short)al0,(short)al0,(short)ah0,(short)a20,(short)ah1,(short)ah1};
            short8 g1 = {(short)al1,(short)al1,(short)ah1,(short)a21,(short)ah2,(short)ah2,(short)al2,(short)al2};
            short8 g2 = {(short)ah2,(short)a22,(short)s0,(short)s1,(short)s2,0,0,0};
            short8 gz = {0,0,0,0,0,0,0,0};
            int base = (t >> 4) * 64 + (t & 15);
            abuf[base + 0]  = g0;
            abuf[base + 16] = g1;
            abuf[base + 32] = g2;
            abuf[base + 48] = gz;
            if (qb == 0)                          // pts4 written exactly once per point
                pts4[pc * PPB + t] = make_float4(x, y, z, fmaf(x, x, fmaf(y, y, z * z)));
        }
        __syncthreads();
        if (cl < 3) {                             // prefetch next chunk's raw coords
            int i1 = (pc + 1) * PPB + t;
            px = pts[i1 * 3 + 0]; py = pts[i1 * 3 + 1]; pz = pts[i1 * 3 + 2];
        }
        float run[8];
#pragma unroll
        for (int f = 0; f < 8; f++) run[f] = FLT_MAX;
        f32x4 zero = {0.f, 0.f, 0.f, 0.f};
#pragma unroll 4
        for (int tt = 0; tt < 32; tt++) {
            short8 a = abuf[tt * 64 + lane];      // lane-contiguous b128: conflict-free
#pragma unroll
            for (int f = 0; f < 8; f++) {
                f32x4 acc = __builtin_amdgcn_mfma_f32_16x16x32_bf16(a, bq[f], zero, 0, 0, 0);
                float t1 = fminf(fminf(acc[0], acc[1]), acc[2]);          // v_min3
                run[f] = fminf(fminf(t1, acc[3]), run[f]);                // v_min3
            }
        }
#pragma unroll
        for (int f = 0; f < 8; f++) {             // merge 4 row-groups, write chunk min
            float v = run[f];
            v = fminf(v, __shfl_xor(v, 16, 64));
            v = fminf(v, __shfl_xor(v, 32, 64));
            if (lane < 16)
                pbvT[(size_t)(qb * 1024 + wave * 128 + f * 16 + lane) * 64 + pc] = v;
        }
    }
}

// ===================== K2: pick =====================
// One wave per query: gmin butterfly + ballot chunk-mask; f32-filtered exact f64
// resolve (lowest-index tie-break == full f64 argmin, validated R1-R7); lanes 0..20
// accumulate the winner's scores into per-segment fixed-point int64 atomics
// (integer adds commute -> deterministic). LAST block (done-counter) computes the
// per-segment argmax (strict >, first max wins) and writes labels in original order.
__global__ __launch_bounds__(512)
void pick(const float4* __restrict__ pts4, const float* __restrict__ dpts,
          const int* __restrict__ sptids, const float* __restrict__ scores,
          const float* __restrict__ pbvT, long long* __restrict__ segsum,
          int* __restrict__ done, float* __restrict__ out, int n, int m)
{
    __shared__ float lab[NSEG];
    __shared__ int last;
    int t = threadIdx.x, wave = t >> 6, lane = t & 63;
    int q = blockIdx.x * 8 + wave;
    if (q < m) {
        float myv = pbvT[(size_t)q * 64 + lane];  // chunk `lane` min (coalesced 256B)
        float g1 = myv;
#pragma unroll
        for (int off = 1; off < 64; off <<= 1) g1 = fminf(g1, __shfl_xor(g1, off, 64));
        float thr = g1 + EPS_PICK;
        unsigned long long msk = __ballot(myv <= thr);   // bit pc == chunk qualifies

        float fx = dpts[q * 3 + 0], fy = dpts[q * 3 + 1], fz = dpts[q * 3 + 2];
        float fm2x = -2.f * fx, fm2y = -2.f * fy, fm2z = -2.f * fz;
        double m2x = -2.0 * (double)fx, m2y = -2.0 * (double)fy, m2z = -2.0 * (double)fz;
        double best = 1e308; int bi = 0x7fffffff;
        while (msk) {
            int pc = __builtin_ctzll(msk); msk &= msk - 1;
            int base = pc * PPB + lane;
#pragma unroll
            for (int r2 = 0; r2 < PPB / 64; r2++) {
                int i = base + r2 * 64;
                if (i < n) {
                    float4 p = pts4[i];
                    float v = fmaf(p.x, fm2x, fmaf(p.y, fm2y, fmaf(p.z, fm2z, p.w)));
                    if (v <= thr) {
                        double ps = (double)p.x * p.x + (double)p.y * p.y + (double)p.z * p.z;
                        double dv = fma((double)p.x, m2x, fma((double)p.y, m2y,
                                    fma((double)p.z, m2z, ps)));
                        if (dv < best || (dv == best && i < bi)) { best = dv; bi = i; }
                    }
                }
            }
        }
#pragma unroll
        for (int off = 32; off; off >>= 1) {
            double ov = __shfl_down(best, off, 64);
            int oi = __shfl_down(bi, off, 64);
            if (ov < best || (ov == best && oi < bi)) { best = ov; bi = oi; }
        }
        int bi0 = __shfl(bi, 0, 64);              // broadcast winner index
        int sg = sptids[q];
        if (lane < C) {                           // fixed-point deterministic accumulation
            double sv = (double)scores[(size_t)bi0 * C + lane] * FPSCALE;
            atomicAdd((unsigned long long*)&segsum[sg * C + lane],
                      (unsigned long long)(long long)sv);
        }
    }
    __threadfence();                              // drain this thread's atomics (release)
    __syncthreads();
    if (t == 0) {
        int old = atomicAdd(done, 1);
        last = (old == (int)gridDim.x - 1) ? 1 : 0;
    }
    __syncthreads();
    if (!last) return;
    __threadfence();                              // acquire: all blocks' sums visible
    if (t < NSEG) {                               // per-segment argmax (exact int64)
        const long long* ss = segsum + t * C;
        long long bv = ss[0]; int best = 0;
#pragma unroll
        for (int c = 1; c < C; c++) {
            long long v = ss[c];
            if (v > bv) { bv = v; best = c; }     // strict > : first max wins
        }
        lab[t] = (float)best;
    }
    __syncthreads();
    for (int i = t; i < m; i += 512)              // labels in ORIGINAL order
        out[(size_t)m * 3 + i] = lab[sptids[i]];
}

extern "C" void kernel_launch(void* const* d_in, const int* in_sizes, int n_in,
                              void* d_out, int out_size, void* d_ws, size_t ws_size,
                              hipStream_t stream) {
    const float* points = (const float*)d_in[0];
    const float* scores = (const float*)d_in[1];
    const float* dpts   = (const float*)d_in[2];
    const int*   sptids = (const int*)d_in[3];

    int n = in_sizes[0] / 3;          // 32768
    int m = in_sizes[2] / 3;          // 16384

    char* ws = (char*)d_ws;
    float4*    pts4   = (float4*)ws;    ws += (size_t)n * sizeof(float4);
    float*     pbvT   = (float*)ws;     ws += (size_t)m * NCHK * sizeof(float);
    long long* segsum = (long long*)ws; ws += (size_t)NSEG * C * sizeof(long long);
    int*       done   = (int*)ws;       ws += 64;

    compute<<<256 + NCHK + 1, 512, 0, stream>>>(points, dpts, sptids,
                                                pts4, pbvT, segsum, done,
                                                (float*)d_out, n, m);
    pick<<<(m + 7) / 8, 512, 0, stream>>>(pts4, dpts, sptids, scores,
                                          pbvT, segsum, done, (float*)d_out, n, m);
}

// Round 10
// 64.211 us; speedup vs baseline: 5.1569x; 4.6268x over previous
//
#include <hip/hip_runtime.h>
#include <cfloat>
#include <cstdint>

#define NSEG 512
#define C 21
#define PPB 512                   // points per chunk
#define NCHK 64                   // n/PPB point chunks == m/256 sptid chunks
#define EPS_PICK 1e-3f            // >= 2*deltaM (MFMA emu) and >= deltaM+delta32 (filter)

typedef short short8 __attribute__((ext_vector_type(8)));     // 8 bf16 (MFMA A/B frag)
typedef float f32x4 __attribute__((ext_vector_type(4)));      // MFMA acc

// truncate r to bf16 (exact split: hi takes the top bits, r -= hi exact in f32)
__device__ inline unsigned short bsplit(float& r) {
    unsigned int u = __float_as_uint(r) & 0xFFFF0000u;
    r -= __uint_as_float(u);
    return (unsigned short)(u >> 16);
}

// ===================== K1: compute =====================
// bid 0..255   : MFMA blocks — self-stage bf16 splits from raw pts/dpts, emulated-f32
//                distance matmul on the matrix pipe, per-chunk min -> pbvT[q][pc].
// bid 256..319 : scatter blocks — self-contained stable counting sort of d_points
//                (points + sorted_orig); block 256 also writes segbase[] (global scan).
// K-slot layout (K=32, 21 used), per coord c (a=-2*p_c, b=q_c):
//   slots 6c..6c+5: A=[ah,ah,al,al,ah,a2]  B=[bh,bl,bh,bl,b2,bh]
//   slots 18..20:   A=|p|^2 hi/lo/lo2  B=[1,1,1];  slots 21..31: 0
__global__ __launch_bounds__(512)
void compute(const float* __restrict__ pts, const float* __restrict__ dpts,
             const int* __restrict__ sptids,
             float4* __restrict__ pts4, float* __restrict__ pbvT,
             int* __restrict__ segbase, int* __restrict__ sorted_orig,
             float* __restrict__ out, int n, int m)
{
    __shared__ short8 abuf[2048];                 // 32 KB (mfma A-tile / scatter scratch)
    const int bid = blockIdx.x, t = threadIdx.x;
    const int wave = t >> 6, lane = t & 63;

    if (bid >= 256) {
        // ---- scatter block sb: self-contained stable counting sort ----
        int sb = bid - 256;
        int* Hb = (int*)abuf;                     // [512] counts with idx < sb*256
        int* Ht = Hb + NSEG;                      // [512] total counts
        int* segs = Ht + NSEG;                    // [256] this chunk's sptids
        Hb[t] = 0; Ht[t] = 0;
        __syncthreads();
        int before = sb * 256;
        for (int idx = t; idx < m; idx += 512) {  // 32 iters; integer LDS atomics
            int s = sptids[idx];
            atomicAdd(&Ht[s], 1);
            if (idx < before) atomicAdd(&Hb[s], 1);
        }
        __syncthreads();
        int s = t;
        int mycnt = Ht[s], myHb = Hb[s];
        int incl = mycnt;                         // inclusive scan of totals (in place)
        for (int off = 1; off < NSEG; off <<= 1) {
            int add = (s >= off) ? Ht[s - off] : 0;
            __syncthreads();
            incl += add; Ht[s] = incl;
            __syncthreads();
        }
        if (sb == 0) segbase[s] = incl - mycnt;   // global segment base (same in all blocks)
        Hb[s] = (incl - mycnt) + myHb;            // seg write base for THIS chunk
        __syncthreads();
        if (t < 256) {
            int i = sb * 256 + t;
            segs[t] = (i < m) ? sptids[i] : -1;
        }
        __syncthreads();
        if (t < 256) {
            int i = sb * 256 + t;
            if (i < m) {
                int seg = segs[t];
                int rank = 0;
                for (int j = 0; j < t; j++) rank += (segs[j] == seg) ? 1 : 0;  // stable
                int pos = Hb[seg] + rank;
                out[pos * 3 + 0] = dpts[i * 3 + 0];
                out[pos * 3 + 1] = dpts[i * 3 + 1];
                out[pos * 3 + 2] = dpts[i * 3 + 2];
                sorted_orig[pos] = i;
            }
        }
        return;
    }

    // ---- MFMA block: emulated-f32 distance matmul + per-chunk min ----
    int qb = bid & 15, cgr = bid >> 4;

    short8 bq[8];                                 // B-frags computed from raw dpts
    {
        const short ONE = (short)0x3F80;          // bf16 1.0
#pragma unroll
        for (int f = 0; f < 8; f++) {
            int qf = qb * 1024 + wave * 128 + f * 16 + (lane & 15);
            float b0 = dpts[qf * 3 + 0], b1 = dpts[qf * 3 + 1], b2c = dpts[qf * 3 + 2];
            float r;
            r = b0;  unsigned short bh0 = bsplit(r), bl0 = bsplit(r), b20 = bsplit(r);
            r = b1;  unsigned short bh1 = bsplit(r), bl1 = bsplit(r), b21 = bsplit(r);
            r = b2c; unsigned short bh2 = bsplit(r), bl2 = bsplit(r), b22 = bsplit(r);
            short8 g0 = {(short)bh0,(short)bl0,(short)bh0,(short)bl0,(short)b20,(short)bh0,(short)bh1,(short)bl1};
            short8 g1 = {(short)bh1,(short)bl1,(short)b21,(short)bh1,(short)bh2,(short)bl2,(short)bh2,(short)bl2};
            short8 g2 = {(short)b22,(short)bh2,ONE,ONE,ONE,0,0,0};
            short8 gz = {0,0,0,0,0,0,0,0};
            int g = lane >> 4;
            bq[f] = (g == 0) ? g0 : (g == 1) ? g1 : (g == 2) ? g2 : gz;
        }
    }

    int c0 = cgr * 4;
    int i0 = c0 * PPB + t;
    float px = pts[i0 * 3 + 0], py = pts[i0 * 3 + 1], pz = pts[i0 * 3 + 2];

    for (int cl = 0; cl < 4; cl++) {
        int pc = c0 + cl;
        if (cl) __syncthreads();                  // prior MFMA readers done with abuf
        {   // stage point t of this chunk: compute A-slots, write frag-major LDS
            float x = px, y = py, z = pz;
            float r;
            float a0 = -2.f * x, a1 = -2.f * y, a2f = -2.f * z;   // exact in f32
            r = a0;  unsigned short ah0 = bsplit(r), al0 = bsplit(r), a20 = bsplit(r);
            r = a1;  unsigned short ah1 = bsplit(r), al1 = bsplit(r), a21 = bsplit(r);
            r = a2f; unsigned short ah2 = bsplit(r), al2 = bsplit(r), a22 = bsplit(r);
            double pr = (double)x * x + (double)y * y + (double)z * z;
            float f0 = (float)pr;
            unsigned int u0 = __float_as_uint(f0) & 0xFFFF0000u;
            pr -= (double)__uint_as_float(u0);
            float f1 = (float)pr;
            unsigned int u1 = __float_as_uint(f1) & 0xFFFF0000u;
            pr -= (double)__uint_as_float(u1);
            float f2 = (float)pr;
            unsigned int u2 = __float_as_uint(f2) & 0xFFFF0000u;
            unsigned short s0 = (unsigned short)(u0 >> 16);
            unsigned short s1 = (unsigned short)(u1 >> 16);
            unsigned short s2 = (unsigned short)(u2 >> 16);
            short8 g0 = {(short)ah0,(short)ah0,(short)al0,(short)al0,(short)ah0,(short)a20,(short)ah1,(short)ah1};
            short8 g1 = {(short)al1,(short)al1,(short)ah1,(short)a21,(short)ah2,(short)ah2,(short)al2,(short)al2};
            short8 g2 = {(short)ah2,(short)a22,(short)s0,(short)s1,(short)s2,0,0,0};
            short8 gz = {0,0,0,0,0,0,0,0};
            int base = (t >> 4) * 64 + (t & 15);
            abuf[base + 0]  = g0;
            abuf[base + 16] = g1;
            abuf[base + 32] = g2;
            abuf[base + 48] = gz;
            if (qb == 0)                          // pts4 written exactly once per point
                pts4[pc * PPB + t] = make_float4(x, y, z, fmaf(x, x, fmaf(y, y, z * z)));
        }
        __syncthreads();
        if (cl < 3) {                             // prefetch next chunk's raw coords
            int i1 = (pc + 1) * PPB + t;
            px = pts[i1 * 3 + 0]; py = pts[i1 * 3 + 1]; pz = pts[i1 * 3 + 2];
        }
        float run[8];
#pragma unroll
        for (int f = 0; f < 8; f++) run[f] = FLT_MAX;
        f32x4 zero = {0.f, 0.f, 0.f, 0.f};
#pragma unroll 4
        for (int tt = 0; tt < 32; tt++) {
            short8 a = abuf[tt * 64 + lane];      // lane-contiguous b128: conflict-free
#pragma unroll
            for (int f = 0; f < 8; f++) {
                f32x4 acc = __builtin_amdgcn_mfma_f32_16x16x32_bf16(a, bq[f], zero, 0, 0, 0);
                float t1 = fminf(fminf(acc[0], acc[1]), acc[2]);          // v_min3
                run[f] = fminf(fminf(t1, acc[3]), run[f]);                // v_min3
            }
        }
#pragma unroll
        for (int f = 0; f < 8; f++) {             // merge 4 row-groups, write chunk min
            float v = run[f];
            v = fminf(v, __shfl_xor(v, 16, 64));
            v = fminf(v, __shfl_xor(v, 32, 64));
            if (lane < 16)
                pbvT[(size_t)(qb * 1024 + wave * 128 + f * 16 + lane) * 64 + pc] = v;
        }
    }
}

// ===================== K2: pick =====================
// One wave per query (no atomics, no fences): lane pc reads pbvT[q][pc] (coalesced),
// butterfly min -> g1; ballot(v<=g1+EPS) -> qualifying-chunk mask; scan those chunks
// with f32 filter; exact f64 eval on survivors; lowest-index tie-break
// == full f64 argmin semantics (validated R1-R9).
__global__ __launch_bounds__(512)
void pick(const float4* __restrict__ pts4, const float* __restrict__ dpts,
          const float* __restrict__ pbvT, int* __restrict__ nn_idx, int n, int m)
{
    int wave = threadIdx.x >> 6, lane = threadIdx.x & 63;
    int q = blockIdx.x * 8 + wave;
    if (q >= m) return;

    float myv = pbvT[(size_t)q * 64 + lane];      // chunk `lane` min (coalesced 256B)
    float g1 = myv;
#pragma unroll
    for (int off = 1; off < 64; off <<= 1) g1 = fminf(g1, __shfl_xor(g1, off, 64));
    float thr = g1 + EPS_PICK;
    unsigned long long msk = __ballot(myv <= thr);   // bit pc == chunk pc qualifies

    float fx = dpts[q * 3 + 0], fy = dpts[q * 3 + 1], fz = dpts[q * 3 + 2];
    float fm2x = -2.f * fx, fm2y = -2.f * fy, fm2z = -2.f * fz;
    double m2x = -2.0 * (double)fx, m2y = -2.0 * (double)fy, m2z = -2.0 * (double)fz;
    double best = 1e308; int bi = 0x7fffffff;
    while (msk) {
        int pc = __builtin_ctzll(msk); msk &= msk - 1;
        int base = pc * PPB + lane;
#pragma unroll
        for (int r2 = 0; r2 < PPB / 64; r2++) {
            int i = base + r2 * 64;
            if (i < n) {
                float4 p = pts4[i];
                float v = fmaf(p.x, fm2x, fmaf(p.y, fm2y, fmaf(p.z, fm2z, p.w)));
                if (v <= thr) {
                    double ps = (double)p.x * p.x + (double)p.y * p.y + (double)p.z * p.z;
                    double dv = fma((double)p.x, m2x, fma((double)p.y, m2y,
                                fma((double)p.z, m2z, ps)));
                    if (dv < best || (dv == best && i < bi)) { best = dv; bi = i; }
                }
            }
        }
    }
#pragma unroll
    for (int off = 32; off; off >>= 1) {
        double ov = __shfl_down(best, off, 64);
        int oi = __shfl_down(bi, off, 64);
        if (ov < best || (ov == best && oi < bi)) { best = ov; bi = oi; }
    }
    if (lane == 0) nn_idx[q] = bi;
}

// ===================== K3: seg_final =====================
// One wave per segment: f64 score sum over the segment's sorted range (via
// nn_idx[sorted_orig[j]]), argmax (strict > : first max wins), labels written
// to original positions. argmax(sum) == argmax(mean).
__global__ __launch_bounds__(512)
void seg_final(const int* __restrict__ segbase, const int* __restrict__ sorted_orig,
               const int* __restrict__ nn_idx, const float* __restrict__ scores,
               float* __restrict__ out, int m)
{
    int wave = threadIdx.x >> 6, lane = threadIdx.x & 63;
    int s = blockIdx.x * 8 + wave;
    if (s >= NSEG) return;
    int base = segbase[s];
    int end  = (s == NSEG - 1) ? m : segbase[s + 1];
    double acc[C];
#pragma unroll
    for (int c = 0; c < C; c++) acc[c] = 0.0;
    for (int j = base + lane; j < end; j += 64) {
        const float* sp = scores + (size_t)nn_idx[sorted_orig[j]] * C;
#pragma unroll
        for (int c = 0; c < C; c++) acc[c] += (double)sp[c];
    }
#pragma unroll
    for (int c = 0; c < C; c++) {
        for (int off = 32; off; off >>= 1) acc[c] += __shfl_down(acc[c], off, 64);
    }
    int best = 0;
    if (lane == 0) {
        double bv = acc[0];
        for (int c = 1; c < C; c++)
            if (acc[c] > bv) { bv = acc[c]; best = c; }   // strict >: first max wins
    }
    best = __shfl(best, 0, 64);
    float fb = (float)best;
    for (int j = base + lane; j < end; j += 64)
        out[(size_t)m * 3 + sorted_orig[j]] = fb;
}

extern "C" void kernel_launch(void* const* d_in, const int* in_sizes, int n_in,
                              void* d_out, int out_size, void* d_ws, size_t ws_size,
                              hipStream_t stream) {
    const float* points = (const float*)d_in[0];
    const float* scores = (const float*)d_in[1];
    const float* dpts   = (const float*)d_in[2];
    const int*   sptids = (const int*)d_in[3];

    int n = in_sizes[0] / 3;          // 32768
    int m = in_sizes[2] / 3;          // 16384

    char* ws = (char*)d_ws;
    float4* pts4        = (float4*)ws;  ws += (size_t)n * sizeof(float4);
    float*  pbvT        = (float*)ws;   ws += (size_t)m * NCHK * sizeof(float);
    int*    nn_idx      = (int*)ws;     ws += (size_t)m * sizeof(int);
    int*    segbase     = (int*)ws;     ws += (size_t)NSEG * sizeof(int);
    int*    sorted_orig = (int*)ws;     ws += (size_t)m * sizeof(int);

    compute<<<256 + NCHK, 512, 0, stream>>>(points, dpts, sptids, pts4, pbvT,
                                            segbase, sorted_orig, (float*)d_out, n, m);
    pick<<<(m + 7) / 8, 512, 0, stream>>>(pts4, dpts, pbvT, nn_idx, n, m);
    seg_final<<<NSEG / 8, 512, 0, stream>>>(segbase, sorted_orig, nn_idx, scores,
                                            (float*)d_out, m);
}

// Round 11
// 60.326 us; speedup vs baseline: 5.4890x; 1.0644x over previous
//
#include <hip/hip_runtime.h>
#include <cfloat>
#include <cstdint>

#define NSEG 512
#define C 21
#define PPB 512                   // points per chunk
#define EPS_PICK 1e-3f            // >= 2*deltaM (MFMA emu) and >= deltaM+delta32 (filter)

typedef short short8 __attribute__((ext_vector_type(8)));     // 8 bf16 (MFMA A/B frag)
typedef float f32x4 __attribute__((ext_vector_type(4)));      // MFMA acc

// truncate r to bf16 (exact split: hi takes the top bits, r -= hi exact in f32)
__device__ inline unsigned short bsplit(float& r) {
    unsigned int u = __float_as_uint(r) & 0xFFFF0000u;
    r -= __uint_as_float(u);
    return (unsigned short)(u >> 16);
}

// ===================== K1: nn_mfma =====================
// Grid (qb=32, pc=64), 256 threads (4 waves). Block: stage chunk pc (512 pts) as
// bf16 split slots in LDS, then each wave computes 128 queries x 512 points of
// emulated-f32 distance on the MATRIX pipe, folding per-chunk min -> pbvT[q][pc].
// 8 MFMAs issued back-to-back per tt (acc[8] live) before any min3 reads results.
// K-slot layout (K=32, 21 used), per coord c (a=-2*p_c, b=q_c):
//   slots 6c..6c+5: A=[ah,ah,al,al,ah,a2]  B=[bh,bl,bh,bl,b2,bh]
//   slots 18..20:   A=|p|^2 hi/lo/lo2  B=[1,1,1];  slots 21..31: 0
__global__ __launch_bounds__(256, 4)
void nn_mfma(const float* __restrict__ pts, const float* __restrict__ dpts,
             float4* __restrict__ pts4, float* __restrict__ pbvT, int n, int m)
{
    __shared__ short8 abuf[2048];                 // 32 KB: one 512-pt chunk, frag-major
    const int t = threadIdx.x;
    const int wave = t >> 6, lane = t & 63;
    const int qb = blockIdx.x, pc = blockIdx.y;

    // ---- B-frags from raw dpts (queries qb*512 + wave*128 + f*16 + row) ----
    short8 bq[8];
    {
        const short ONE = (short)0x3F80;          // bf16 1.0
#pragma unroll
        for (int f = 0; f < 8; f++) {
            int qf = qb * 512 + wave * 128 + f * 16 + (lane & 15);
            float b0 = dpts[qf * 3 + 0], b1 = dpts[qf * 3 + 1], b2c = dpts[qf * 3 + 2];
            float r;
            r = b0;  unsigned short bh0 = bsplit(r), bl0 = bsplit(r), b20 = bsplit(r);
            r = b1;  unsigned short bh1 = bsplit(r), bl1 = bsplit(r), b21 = bsplit(r);
            r = b2c; unsigned short bh2 = bsplit(r), bl2 = bsplit(r), b22 = bsplit(r);
            short8 g0 = {(short)bh0,(short)bl0,(short)bh0,(short)bl0,(short)b20,(short)bh0,(short)bh1,(short)bl1};
            short8 g1 = {(short)bh1,(short)bl1,(short)b21,(short)bh1,(short)bh2,(short)bl2,(short)bh2,(short)bl2};
            short8 g2 = {(short)b22,(short)bh2,ONE,ONE,ONE,0,0,0};
            short8 gz = {0,0,0,0,0,0,0,0};
            int g = lane >> 4;
            bq[f] = (g == 0) ? g0 : (g == 1) ? g1 : (g == 2) ? g2 : gz;
        }
    }

    // ---- stage chunk pc: each thread stages points t and t+256 ----
#pragma unroll
    for (int half = 0; half < 2; half++) {
        int j = half * 256 + t;                   // 0..511 within chunk
        int i = pc * PPB + j;
        float x = pts[i * 3 + 0], y = pts[i * 3 + 1], z = pts[i * 3 + 2];
        float r;
        float a0 = -2.f * x, a1 = -2.f * y, a2f = -2.f * z;   // exact in f32
        r = a0;  unsigned short ah0 = bsplit(r), al0 = bsplit(r), a20 = bsplit(r);
        r = a1;  unsigned short ah1 = bsplit(r), al1 = bsplit(r), a21 = bsplit(r);
        r = a2f; unsigned short ah2 = bsplit(r), al2 = bsplit(r), a22 = bsplit(r);
        double pr = (double)x * x + (double)y * y + (double)z * z;
        float f0 = (float)pr;
        unsigned int u0 = __float_as_uint(f0) & 0xFFFF0000u;
        pr -= (double)__uint_as_float(u0);
        float f1 = (float)pr;
        unsigned int u1 = __float_as_uint(f1) & 0xFFFF0000u;
        pr -= (double)__uint_as_float(u1);
        float f2 = (float)pr;
        unsigned int u2 = __float_as_uint(f2) & 0xFFFF0000u;
        unsigned short s0 = (unsigned short)(u0 >> 16);
        unsigned short s1 = (unsigned short)(u1 >> 16);
        unsigned short s2 = (unsigned short)(u2 >> 16);
        short8 g0 = {(short)ah0,(short)ah0,(short)al0,(short)al0,(short)ah0,(short)a20,(short)ah1,(short)ah1};
        short8 g1 = {(short)al1,(short)al1,(short)ah1,(short)a21,(short)ah2,(short)ah2,(short)al2,(short)al2};
        short8 g2 = {(short)ah2,(short)a22,(short)s0,(short)s1,(short)s2,0,0,0};
        short8 gz = {0,0,0,0,0,0,0,0};
        int base = (j >> 4) * 64 + (j & 15);
        abuf[base + 0]  = g0;
        abuf[base + 16] = g1;
        abuf[base + 32] = g2;
        abuf[base + 48] = gz;
        if (qb == 0)                              // pts4 written exactly once per point
            pts4[i] = make_float4(x, y, z, fmaf(x, x, fmaf(y, y, z * z)));
    }
    __syncthreads();

    // ---- MFMA loop: 32 A-tiles x 8 B-frags ----
    float run[8];
#pragma unroll
    for (int f = 0; f < 8; f++) run[f] = FLT_MAX;
    const f32x4 zero = {0.f, 0.f, 0.f, 0.f};
#pragma unroll 2
    for (int tt = 0; tt < 32; tt++) {
        short8 a = abuf[tt * 64 + lane];          // lane-contiguous b128: conflict-free
        f32x4 acc[8];
#pragma unroll
        for (int f = 0; f < 8; f++)               // 8 independent MFMAs in flight
            acc[f] = __builtin_amdgcn_mfma_f32_16x16x32_bf16(a, bq[f], zero, 0, 0, 0);
#pragma unroll
        for (int f = 0; f < 8; f++) {             // then fold (v_min3 x2)
            float t1 = fminf(fminf(acc[f][0], acc[f][1]), acc[f][2]);
            run[f] = fminf(fminf(t1, acc[f][3]), run[f]);
        }
    }
#pragma unroll
    for (int f = 0; f < 8; f++) {                 // merge 4 row-groups, write chunk min
        float v = run[f];
        v = fminf(v, __shfl_xor(v, 16, 64));
        v = fminf(v, __shfl_xor(v, 32, 64));
        if (lane < 16)
            pbvT[(size_t)(qb * 512 + wave * 128 + f * 16 + lane) * 64 + pc] = v;
    }
}

// ===================== K2: pick_scatter =====================
// bid < PICKB : one wave per query — lane pc reads pbvT[q][pc] (coalesced), butterfly
//   min -> g1; ballot(v<=g1+EPS) -> qualifying-chunk mask; f32-filtered exact f64
//   resolve, lowest-index tie-break == full f64 argmin (validated R1-R10) -> nn_idx.
// bid >= PICKB: scatter blocks — self-contained stable counting sort of d_points
//   (points + sorted_orig); first scatter block also writes segbase[].
__global__ __launch_bounds__(512)
void pick_scatter(const float4* __restrict__ pts4, const float* __restrict__ dpts,
                  const int* __restrict__ sptids, const float* __restrict__ pbvT,
                  int* __restrict__ nn_idx, int* __restrict__ segbase,
                  int* __restrict__ sorted_orig, float* __restrict__ out,
                  int n, int m, int PICKB)
{
    __shared__ int lds[NSEG * 2 + 256];
    const int bid = blockIdx.x, t = threadIdx.x;

    if (bid >= PICKB) {
        // ---- scatter block sb: self-contained stable counting sort ----
        int sb = bid - PICKB;
        int* Hb = lds;                            // [512] counts with idx < sb*256
        int* Ht = Hb + NSEG;                      // [512] total counts
        int* segs = Ht + NSEG;                    // [256] this chunk's sptids
        Hb[t] = 0; Ht[t] = 0;
        __syncthreads();
        int before = sb * 256;
        for (int idx = t; idx < m; idx += 512) {  // integer LDS atomics
            int s = sptids[idx];
            atomicAdd(&Ht[s], 1);
            if (idx < before) atomicAdd(&Hb[s], 1);
        }
        __syncthreads();
        int s = t;
        int mycnt = Ht[s], myHb = Hb[s];
        int incl = mycnt;                         // inclusive scan of totals (in place)
        for (int off = 1; off < NSEG; off <<= 1) {
            int add = (s >= off) ? Ht[s - off] : 0;
            __syncthreads();
            incl += add; Ht[s] = incl;
            __syncthreads();
        }
        if (sb == 0) segbase[s] = incl - mycnt;   // global segment base
        Hb[s] = (incl - mycnt) + myHb;            // seg write base for THIS chunk
        __syncthreads();
        if (t < 256) {
            int i = sb * 256 + t;
            segs[t] = (i < m) ? sptids[i] : -1;
        }
        __syncthreads();
        if (t < 256) {
            int i = sb * 256 + t;
            if (i < m) {
                int seg = segs[t];
                int rank = 0;
                for (int j = 0; j < t; j++) rank += (segs[j] == seg) ? 1 : 0;  // stable
                int pos = Hb[seg] + rank;
                out[pos * 3 + 0] = dpts[i * 3 + 0];
                out[pos * 3 + 1] = dpts[i * 3 + 1];
                out[pos * 3 + 2] = dpts[i * 3 + 2];
                sorted_orig[pos] = i;
            }
        }
        return;
    }

    // ---- pick: one wave per query ----
    int wave = t >> 6, lane = t & 63;
    int q = bid * 8 + wave;
    if (q >= m) return;

    float myv = pbvT[(size_t)q * 64 + lane];      // chunk `lane` min (coalesced 256B)
    float g1 = myv;
#pragma unroll
    for (int off = 1; off < 64; off <<= 1) g1 = fminf(g1, __shfl_xor(g1, off, 64));
    float thr = g1 + EPS_PICK;
    unsigned long long msk = __ballot(myv <= thr);   // bit pc == chunk pc qualifies

    float fx = dpts[q * 3 + 0], fy = dpts[q * 3 + 1], fz = dpts[q * 3 + 2];
    float fm2x = -2.f * fx, fm2y = -2.f * fy, fm2z = -2.f * fz;
    double m2x = -2.0 * (double)fx, m2y = -2.0 * (double)fy, m2z = -2.0 * (double)fz;
    double best = 1e308; int bi = 0x7fffffff;
    while (msk) {
        int pc = __builtin_ctzll(msk); msk &= msk - 1;
        int base = pc * PPB + lane;
#pragma unroll
        for (int r2 = 0; r2 < PPB / 64; r2++) {
            int i = base + r2 * 64;
            if (i < n) {
                float4 p = pts4[i];
                float v = fmaf(p.x, fm2x, fmaf(p.y, fm2y, fmaf(p.z, fm2z, p.w)));
                if (v <= thr) {
                    double ps = (double)p.x * p.x + (double)p.y * p.y + (double)p.z * p.z;
                    double dv = fma((double)p.x, m2x, fma((double)p.y, m2y,
                                fma((double)p.z, m2z, ps)));
                    if (dv < best || (dv == best && i < bi)) { best = dv; bi = i; }
                }
            }
        }
    }
#pragma unroll
    for (int off = 32; off; off >>= 1) {
        double ov = __shfl_down(best, off, 64);
        int oi = __shfl_down(bi, off, 64);
        if (ov < best || (ov == best && oi < bi)) { best = ov; bi = oi; }
    }
    if (lane == 0) nn_idx[q] = bi;
}

// ===================== K3: seg_final =====================
// One wave per segment: f64 score sum over the segment's sorted range (via
// nn_idx[sorted_orig[j]]), argmax (strict > : first max wins), labels written
// to original positions. argmax(sum) == argmax(mean).
__global__ __launch_bounds__(512)
void seg_final(const int* __restrict__ segbase, const int* __restrict__ sorted_orig,
               const int* __restrict__ nn_idx, const float* __restrict__ scores,
               float* __restrict__ out, int m)
{
    int wave = threadIdx.x >> 6, lane = threadIdx.x & 63;
    int s = blockIdx.x * 8 + wave;
    if (s >= NSEG) return;
    int base = segbase[s];
    int end  = (s == NSEG - 1) ? m : segbase[s + 1];
    double acc[C];
#pragma unroll
    for (int c = 0; c < C; c++) acc[c] = 0.0;
    for (int j = base + lane; j < end; j += 64) {
        const float* sp = scores + (size_t)nn_idx[sorted_orig[j]] * C;
#pragma unroll
        for (int c = 0; c < C; c++) acc[c] += (double)sp[c];
    }
#pragma unroll
    for (int c = 0; c < C; c++) {
        for (int off = 32; off; off >>= 1) acc[c] += __shfl_down(acc[c], off, 64);
    }
    int best = 0;
    if (lane == 0) {
        double bv = acc[0];
        for (int c = 1; c < C; c++)
            if (acc[c] > bv) { bv = acc[c]; best = c; }   // strict >: first max wins
    }
    best = __shfl(best, 0, 64);
    float fb = (float)best;
    for (int j = base + lane; j < end; j += 64)
        out[(size_t)m * 3 + sorted_orig[j]] = fb;
}

extern "C" void kernel_launch(void* const* d_in, const int* in_sizes, int n_in,
                              void* d_out, int out_size, void* d_ws, size_t ws_size,
                              hipStream_t stream) {
    const float* points = (const float*)d_in[0];
    const float* scores = (const float*)d_in[1];
    const float* dpts   = (const float*)d_in[2];
    const int*   sptids = (const int*)d_in[3];

    int n = in_sizes[0] / 3;          // 32768
    int m = in_sizes[2] / 3;          // 16384
    int QB  = (m + 511) / 512;        // 32 query blocks
    int PCg = (n + 511) / 512;        // 64 point chunks
    int NCH = (m + 255) / 256;        // 64 scatter chunks
    int PICKB = (m + 7) / 8;          // 2048 pick blocks

    char* ws = (char*)d_ws;
    float4* pts4        = (float4*)ws;  ws += (size_t)n * sizeof(float4);
    float*  pbvT        = (float*)ws;   ws += (size_t)m * 64 * sizeof(float);
    int*    nn_idx      = (int*)ws;     ws += (size_t)m * sizeof(int);
    int*    segbase     = (int*)ws;     ws += (size_t)NSEG * sizeof(int);
    int*    sorted_orig = (int*)ws;     ws += (size_t)m * sizeof(int);

    nn_mfma<<<dim3(QB, PCg), 256, 0, stream>>>(points, dpts, pts4, pbvT, n, m);
    pick_scatter<<<PICKB + NCH, 512, 0, stream>>>(pts4, dpts, sptids, pbvT,
                                                  nn_idx, segbase, sorted_orig,
                                                  (float*)d_out, n, m, PICKB);
    seg_final<<<NSEG / 8, 512, 0, stream>>>(segbase, sorted_orig, nn_idx, scores,
                                            (float*)d_out, m);
}